// Round 5
// baseline (62.914 us; speedup 1.0000x reference)
//
#include <hip/hip_runtime.h>

// out[b,c,m] = sum_{j=0}^{127} x[b, (128m - j) mod 16000] * (kr[c,j] + i*ki[c,j])
//   x: (32, 1, 16000) fp32; kernels: (40, 128) fp32
//   out: (32, 40, 125) complex64 -> planar [all re | all im] (confirmed round 2)
//
// Round 5: register-block over m — each thread computes TWO outputs (m, m+62),
// so every LDS kernel read feeds 4 FMAs (was 2), and fp32 float2 LDS kills the
// bf16 unpack VALU. Adjacent taps paired into aligned float2 x loads.
#define BB      32
#define CC      40
#define LL      16000
#define KK      128
#define MM      125
#define KPAD2   129                 // float2 row stride: bank = (2c+2j)%32 -> <=3-way
#define NOUT    (BB * CC * MM)      // 160000 complex outputs
#define MSLOTS  63                  // m1 = 0..62, m2 = m1+62 = 62..124 (m=62 dup, benign)
#define BLK     128
#define NTHR    (BB * MSLOTS * CC)  // 80640 = 630 * 128 exact

__global__ __launch_bounds__(BLK) void ISAC_conv_kernel(
    const float* __restrict__ x,     // B*L
    const float* __restrict__ kr,    // C*K
    const float* __restrict__ ki,    // C*K
    float*       __restrict__ out,   // layout per `mode`
    int mode)                        // 0=planar, 1=real-only, 2=interleaved
{
    __shared__ float2 skc[CC * KPAD2];   // (kr, ki) fp32 interleaved, ~41.3 KB

    // Stage kernels into LDS (float2 global reads, 2 taps per iteration)
    for (int i = threadIdx.x; i < CC * KK / 2; i += BLK) {
        int c  = i >> 6;              // tap-pair rows of 64
        int jp = (i & 63) << 1;       // even tap index
        float2 r2 = *reinterpret_cast<const float2*>(kr + c * KK + jp);
        float2 i2 = *reinterpret_cast<const float2*>(ki + c * KK + jp);
        skc[c * KPAD2 + jp]     = make_float2(r2.x, i2.x);
        skc[c * KPAD2 + jp + 1] = make_float2(r2.y, i2.y);
    }
    __syncthreads();

    // c fastest -> a wave's x loads touch <=2 cache lines (broadcast-like)
    int id = blockIdx.x * BLK + threadIdx.x;   // 0..80639 (exact grid)
    int c  = id % CC;
    int s  = id / CC;                          // = b*63 + mslot
    int m1 = s % MSLOTS;
    int b  = s / MSLOTS;
    int m2 = m1 + 62;                          // 62..124

    const float2* kc = skc + c * KPAD2;
    const float*  xb = x + b * LL;
    const int base1 = m1 * KK, base2 = m2 * KK;
    // Wrap hoisted: only m==0 can go negative for j>=1.
    const float* p1 = xb + (m1 == 0 ? LL : base1);
    const float* p2 = xb + base2;

    float2 k0 = kc[0];
    float xv1 = xb[base1], xv2 = xb[base2];
    float ar1 = xv1 * k0.x, ai1 = xv1 * k0.y;
    float ar2 = xv2 * k0.x, ai2 = xv2 * k0.y;

    // Pairs (j=jo, jo+1), jo odd: float2 at p-jo-1 is 8B-aligned (base even).
    //   xp.x = x at tap jo+1, xp.y = x at tap jo.
#pragma unroll
    for (int jo = 1; jo < KK - 1; jo += 2) {
        float2 xp1 = *reinterpret_cast<const float2*>(p1 - jo - 1);
        float2 xp2 = *reinterpret_cast<const float2*>(p2 - jo - 1);
        float2 ka  = kc[jo];
        float2 kb2 = kc[jo + 1];
        ar1 = fmaf(xp1.y, ka.x,  ar1);  ai1 = fmaf(xp1.y, ka.y,  ai1);
        ar2 = fmaf(xp2.y, ka.x,  ar2);  ai2 = fmaf(xp2.y, ka.y,  ai2);
        ar1 = fmaf(xp1.x, kb2.x, ar1);  ai1 = fmaf(xp1.x, kb2.y, ai1);
        ar2 = fmaf(xp2.x, kb2.x, ar2);  ai2 = fmaf(xp2.x, kb2.y, ai2);
    }
    {   // j = 127 (tail tap)
        float xt1 = p1[-(KK - 1)], xt2 = p2[-(KK - 1)];
        float2 kl = kc[KK - 1];
        ar1 = fmaf(xt1, kl.x, ar1);  ai1 = fmaf(xt1, kl.y, ai1);
        ar2 = fmaf(xt2, kl.x, ar2);  ai2 = fmaf(xt2, kl.y, ai2);
    }

    int o1 = (b * CC + c) * MM + m1;
    int o2 = (b * CC + c) * MM + m2;
    if (mode == 0) {
        out[o1]        = ar1;  out[NOUT + o1] = ai1;   // planar re | im
        out[o2]        = ar2;  out[NOUT + o2] = ai2;
    } else if (mode == 1) {
        out[o1] = ar1;  out[o2] = ar2;
    } else {
        reinterpret_cast<float2*>(out)[o1] = make_float2(ar1, ai1);
        reinterpret_cast<float2*>(out)[o2] = make_float2(ar2, ai2);
    }
}

extern "C" void kernel_launch(void* const* d_in, const int* in_sizes, int n_in,
                              void* d_out, int out_size, void* d_ws, size_t ws_size,
                              hipStream_t stream) {
    const float* x  = (const float*)d_in[0];
    const float* kr = (const float*)d_in[1];
    const float* ki = (const float*)d_in[2];
    float* out = (float*)d_out;

    int mode;
    if (out_size == 2 * NOUT)      mode = 0;   // planar re|im (confirmed)
    else if (out_size == NOUT)     mode = 1;
    else                           mode = 2;

    const int grid = NTHR / BLK;               // 630, exact
    ISAC_conv_kernel<<<grid, BLK, 0, stream>>>(x, kr, ki, out, mode);
}